// Round 10
// baseline (204.702 us; speedup 1.0000x reference)
//
#include <hip/hip_runtime.h>
#include <cstdint>
#include <cstddef>

// Problem constants
#define N_   4096
#define T_   8
#define K_   4
#define R_   8
#define DK_  64
#define S_   2
#define B_   20
#define NT_  (N_*T_)

// ---------------------------------------------------------------------------
// top-4 machinery: order-preserving u64 key = (ordered_uint(value)<<32) | ~col
// larger key == larger value; tie -> smaller col wins (matches jax.lax.top_k)
// ---------------------------------------------------------------------------
__device__ __forceinline__ unsigned long long mkkey(float v, int col) {
    unsigned u = __float_as_uint(v);
    u = (u & 0x80000000u) ? ~u : (u | 0x80000000u);
    return ((unsigned long long)u << 32) | (unsigned)(~col);
}

#define INS4(t0,t1,t2,t3,keyexpr) do {                                  \
    unsigned long long _k = (keyexpr);                                  \
    if (_k > (t3)) {                                                    \
        bool _g2 = _k > (t2), _g1 = _k > (t1), _g0 = _k > (t0);         \
        (t3) = _g2 ? (t2) : _k;                                         \
        (t2) = _g2 ? (_g1 ? (t1) : _k) : (t2);                          \
        (t1) = _g1 ? (_g0 ? (t0) : _k) : (t1);                          \
        (t0) = _g0 ? _k : (t0);                                         \
    }                                                                   \
} while (0)

__device__ __forceinline__ unsigned long long shfl_xor_u64(unsigned long long v, int m) {
    unsigned lo = (unsigned)v, hi = (unsigned)(v >> 32);
    lo = __shfl_xor(lo, m, 64);
    hi = __shfl_xor(hi, m, 64);
    return ((unsigned long long)hi << 32) | lo;
}

#define WST 708

// ---------------------------------------------------------------------------
// Kernel A: proj + prep in ONE dispatch (unchanged from R8).
// ---------------------------------------------------------------------------
__global__ __launch_bounds__(256) void proj_prep_kernel(
    const float* __restrict__ obs, const float* __restrict__ obsv,
    const float* __restrict__ wq_ctx, const float* __restrict__ bq_ctx,
    const float* __restrict__ wk_ctx, const float* __restrict__ bk_ctx,
    const float* __restrict__ wq_rule, const float* __restrict__ bq_rule,
    const float* __restrict__ rule_emb,
    const float* __restrict__ sp_w, const float* __restrict__ sp_b,
    const float* __restrict__ spr_w, const float* __restrict__ spr_b,
    const float* __restrict__ tp_w, const float* __restrict__ tp_b,
    const float* __restrict__ tpr_w, const float* __restrict__ tpr_b,
    const float* __restrict__ spi_w, const float* __restrict__ spi_b,
    const float* __restrict__ spir_w, const float* __restrict__ spir_b,
    const float* __restrict__ tpi_w, const float* __restrict__ tpi_b,
    const float* __restrict__ tpir_w, const float* __restrict__ tpir_b,
    float* __restrict__ qg, float* __restrict__ kg, int* __restrict__ rid,
    float* __restrict__ Wpk)
{
    if (blockIdx.x >= N_/4) {
        int r = blockIdx.x - N_/4;
        for (int o = threadIdx.x; o < 704; o += 256) {
            float v;
            if (o < 12)      v = spi_w[r*12 + o];
            else if (o < 16) v = spir_w[r*4 + (o-12)];
            else if (o < 76) v = sp_w[r*60 + (o-16)];
            else if (o < 96) v = spr_w[r*20 + (o-76)];
            else if (o < 192) { int q=o-96;  int t=q/12, co=q%12; v = tpi_w[((r*12+co)*8+t)*3+1] + tpir_w[(r*12+co)*8+t]; }
            else if (o < 288) { int q=o-192; int t=q/12, co=q%12; v = tpi_w[((r*12+co)*8+t)*3+2]; }
            else if (o < 384) { int q=o-288; int t=q/12, co=q%12; v = tpi_w[((r*12+co)*8+t)*3+0]; }
            else if (o < 480) { int q=o-384; int t=q/12, co=q%12; v = tp_w[((r*12+co)*8+t)*3+1] + tpr_w[(r*12+co)*8+t]; }
            else if (o < 576) { int q=o-480; int t=q/12, co=q%12; v = tp_w[((r*12+co)*8+t)*3+2]; }
            else if (o < 672) { int q=o-576; int t=q/12, co=q%12; v = tp_w[((r*12+co)*8+t)*3+0]; }
            else if (o < 674) v = spi_b[r*2 + (o-672)];
            else if (o < 676) v = spir_b[r*2 + (o-674)];
            else if (o < 678) v = sp_b[r*2 + (o-676)];
            else if (o < 680) v = spr_b[r*2 + (o-678)];
            else if (o < 692) v = tpi_b[r*12 + (o-680)] + tpir_b[r*12 + (o-680)];
            else              v = tp_b[r*12 + (o-692)] + tpr_b[r*12 + (o-692)];
            Wpk[r*WST + o] = v;
        }
        return;
    }

    int wv = threadIdx.x >> 6, d = threadIdx.x & 63;
    int n = blockIdx.x * 4 + wv;
    __shared__ float xs[4][32];
    if (d < 32) {
        int t = d >> 2, c = d & 3;
        const float* src = (c < 2) ? obs : obsv;
        xs[wv][d] = src[(c & 1) * NT_ + n * T_ + t];
    }
    __syncthreads();
    const float* x = xs[wv];
    float q = bq_ctx[d], k = bk_ctx[d], rq = bq_rule[d];
    #pragma unroll
    for (int i = 0; i < 32; ++i) {
        float xv = x[i];
        q = fmaf(xv, wq_ctx[i*64 + d], q);
        k = fmaf(xv, wk_ctx[i*64 + d], k);
    }
    #pragma unroll
    for (int i = 0; i < 16; ++i) {
        int t = i >> 1, s = i & 1;
        rq = fmaf(x[t*4 + 2 + s], wq_rule[i*64 + d], rq);
    }
    qg[n*64 + d] = q;
    kg[n*64 + d] = k;

    float best = -1e30f; int bestr = 0;
    #pragma unroll
    for (int r = 0; r < 8; ++r) {
        float p = rq * rule_emb[r*64 + d];
        #pragma unroll
        for (int off = 32; off > 0; off >>= 1) p += __shfl_xor(p, off, 64);
        if (p > best) { best = p; bestr = r; }
    }
    if (d == 0) rid[n] = bestr;
}

// ---------------------------------------------------------------------------
// Kernel B (R9): 8x8 per-thread tile -> 1 B LDS per FMA (was 1.5).
// 256 thr as 16tx x 16ty; thread owns rows {4ty..+3, 64+4ty..+3} x cols
// {4tx..+3, 64+4tx..+3} of a 128x128 macro-tile.  ROWS use the same split
// trick as cols: 4ty/64+4ty keeps the two a-frag b128 reads 2-way-per-bank
// (free per m136); a contiguous 8ty layout would be 4-way conflicted.
// All 4 b128 reads/d for 64 fma: traffic 1.07 GB, pipe floor ~20.5 µs
// (R7 = 1.6 GB / 30.6 µs floor, measured 67).  LDS 64 KB -> 2 blocks/CU
// = 8 waves/CU; per-wave fma burst per d doubles (128 cyc vs 64) against
// 48 cyc LDS service, so ILP substitutes for the halved TLP.
// Grid = 32 rowblks x NSPLIT 16 = 512 = exact 2/CU packing.
// ---------------------------------------------------------------------------
#define RPB     128                  // rows per block
#define CTILE   128                  // cols per LDS tile
#define NSPLIT  16                   // col splits; 4096/16 = 256 cols/block
#define KST2    128                  // [d][*] stride (floats, no pad)

__global__ __launch_bounds__(256) void attn_topk_kernel(
    const float* __restrict__ qg, const float* __restrict__ kg,
    unsigned long long* __restrict__ part)
{
    __shared__ float qT[DK_*KST2];                  // 32768 B
    __shared__ float kT[DK_*KST2];                  // 32768 B

    int tid = threadIdx.x;
    int tx = tid & 15, ty = tid >> 4;               // both 0..15
    int rowblk = blockIdx.x >> 4, split = blockIdx.x & 15;
    int row0 = rowblk * RPB;
    int colbase = split * (N_ / NSPLIT);

    // stage qT[d][row]: 128 rows x 16 dchunks = 2048 chunks, 8 iters.
    // row==(chunk&127): within a wave rows are lane-consecutive -> LDS write
    // banks 2-way free (row%32); global reads 256B-strided but L2-resident.
    #pragma unroll
    for (int i = 0; i < 8; ++i) {
        int chunk = tid + 256*i;
        int row = chunk & 127, dc = chunk >> 7;
        float4 v = *(const float4*)(qg + (size_t)(row0 + row)*64 + 4*dc);
        qT[(4*dc+0)*KST2 + row] = v.x;
        qT[(4*dc+1)*KST2 + row] = v.y;
        qT[(4*dc+2)*KST2 + row] = v.z;
        qT[(4*dc+3)*KST2 + row] = v.w;
    }

    // top-4 state: 8 row-groups x 4 slots, named scalars
    unsigned long long T0a=0,T0b=0,T0c=0,T0d=0, T1a=0,T1b=0,T1c=0,T1d=0;
    unsigned long long T2a=0,T2b=0,T2c=0,T2d=0, T3a=0,T3b=0,T3c=0,T3d=0;
    unsigned long long T4a=0,T4b=0,T4c=0,T4d=0, T5a=0,T5b=0,T5c=0,T5d=0;
    unsigned long long T6a=0,T6b=0,T6c=0,T6d=0, T7a=0,T7b=0,T7c=0,T7d=0;

    for (int tile = 0; tile < (N_/NSPLIT)/CTILE; ++tile) {   // 2 tiles
        int c0 = colbase + tile * CTILE;
        __syncthreads();                            // kT free
        #pragma unroll
        for (int i = 0; i < 8; ++i) {
            int chunk = tid + 256*i;
            int col = chunk & 127, dc = chunk >> 7;
            float4 v = *(const float4*)(kg + (size_t)(c0 + col)*64 + 4*dc);
            kT[(4*dc+0)*KST2 + col] = v.x;
            kT[(4*dc+1)*KST2 + col] = v.y;
            kT[(4*dc+2)*KST2 + col] = v.z;
            kT[(4*dc+3)*KST2 + col] = v.w;
        }
        __syncthreads();

        float acc[8][8];
        #pragma unroll
        for (int i = 0; i < 8; ++i)
            #pragma unroll
            for (int j = 0; j < 8; ++j) acc[i][j] = 0.f;

        #pragma unroll 2
        for (int d = 0; d < 64; ++d) {
            float4 a0 = *(const float4*)(&qT[d*KST2 + 4*ty]);         // 2-way free
            float4 a1 = *(const float4*)(&qT[d*KST2 + 64 + 4*ty]);    // 2-way free
            float4 b0 = *(const float4*)(&kT[d*KST2 + 4*tx]);         // 2-way free
            float4 b1 = *(const float4*)(&kT[d*KST2 + 64 + 4*tx]);    // 2-way free
            float av[8] = {a0.x, a0.y, a0.z, a0.w, a1.x, a1.y, a1.z, a1.w};
            float bv[8] = {b0.x, b0.y, b0.z, b0.w, b1.x, b1.y, b1.z, b1.w};
            #pragma unroll
            for (int i = 0; i < 8; ++i)
                #pragma unroll
                for (int j = 0; j < 8; ++j)
                    acc[i][j] = fmaf(av[i], bv[j], acc[i][j]);
        }
        int ccA = c0 + 4*tx, ccB = c0 + 64 + 4*tx;
        #define ROW8(t0,t1,t2,t3,i) do {                         \
            INS4(t0,t1,t2,t3, mkkey(acc[i][0], ccA+0));          \
            INS4(t0,t1,t2,t3, mkkey(acc[i][1], ccA+1));          \
            INS4(t0,t1,t2,t3, mkkey(acc[i][2], ccA+2));          \
            INS4(t0,t1,t2,t3, mkkey(acc[i][3], ccA+3));          \
            INS4(t0,t1,t2,t3, mkkey(acc[i][4], ccB+0));          \
            INS4(t0,t1,t2,t3, mkkey(acc[i][5], ccB+1));          \
            INS4(t0,t1,t2,t3, mkkey(acc[i][6], ccB+2));          \
            INS4(t0,t1,t2,t3, mkkey(acc[i][7], ccB+3));          \
        } while (0)
        ROW8(T0a,T0b,T0c,T0d, 0);
        ROW8(T1a,T1b,T1c,T1d, 1);
        ROW8(T2a,T2b,T2c,T2d, 2);
        ROW8(T3a,T3b,T3c,T3d, 3);
        ROW8(T4a,T4b,T4c,T4d, 4);
        ROW8(T5a,T5b,T5c,T5d, 5);
        ROW8(T6a,T6b,T6c,T6d, 6);
        ROW8(T7a,T7b,T7c,T7d, 7);
        #undef ROW8
    }

    // butterfly merge across the 16 tx lanes (masks 1..8 stay in-group).
    // SNAPSHOT partner keys before merging (lockstep hazard), then INS4.
    #define MRG(a,b,c,dd,m) do {                                          \
        unsigned long long r0 = shfl_xor_u64(a, m), r1 = shfl_xor_u64(b, m); \
        unsigned long long r2 = shfl_xor_u64(c, m), r3 = shfl_xor_u64(dd, m);\
        INS4(a,b,c,dd, r0); INS4(a,b,c,dd, r1);                           \
        INS4(a,b,c,dd, r2); INS4(a,b,c,dd, r3);                           \
    } while (0)
    #pragma unroll
    for (int m = 1; m < 16; m <<= 1) {
        MRG(T0a,T0b,T0c,T0d, m);
        MRG(T1a,T1b,T1c,T1d, m);
        MRG(T2a,T2b,T2c,T2d, m);
        MRG(T3a,T3b,T3c,T3d, m);
        MRG(T4a,T4b,T4c,T4d, m);
        MRG(T5a,T5b,T5c,T5d, m);
        MRG(T6a,T6b,T6c,T6d, m);
        MRG(T7a,T7b,T7c,T7d, m);
    }
    #undef MRG

    if (tx == 0) {
        unsigned long long* q;
        q = &part[(size_t)((row0 + 4*ty + 0)*NSPLIT + split)*4];
        q[0]=T0a; q[1]=T0b; q[2]=T0c; q[3]=T0d;
        q = &part[(size_t)((row0 + 4*ty + 1)*NSPLIT + split)*4];
        q[0]=T1a; q[1]=T1b; q[2]=T1c; q[3]=T1d;
        q = &part[(size_t)((row0 + 4*ty + 2)*NSPLIT + split)*4];
        q[0]=T2a; q[1]=T2b; q[2]=T2c; q[3]=T2d;
        q = &part[(size_t)((row0 + 4*ty + 3)*NSPLIT + split)*4];
        q[0]=T3a; q[1]=T3b; q[2]=T3c; q[3]=T3d;
        q = &part[(size_t)((row0 + 64 + 4*ty + 0)*NSPLIT + split)*4];
        q[0]=T4a; q[1]=T4b; q[2]=T4c; q[3]=T4d;
        q = &part[(size_t)((row0 + 64 + 4*ty + 1)*NSPLIT + split)*4];
        q[0]=T5a; q[1]=T5b; q[2]=T5c; q[3]=T5d;
        q = &part[(size_t)((row0 + 64 + 4*ty + 2)*NSPLIT + split)*4];
        q[0]=T6a; q[1]=T6b; q[2]=T6c; q[3]=T6d;
        q = &part[(size_t)((row0 + 64 + 4*ty + 3)*NSPLIT + split)*4];
        q[0]=T7a; q[1]=T7b; q[2]=T7c; q[3]=T7d;
    }
}

// ---------------------------------------------------------------------------
// Kernel C: merge + predict fused (unchanged from R8).
// ---------------------------------------------------------------------------
__global__ __launch_bounds__(320) void predict_kernel(
    const float* __restrict__ obsv, const float* __restrict__ noise,
    const float* __restrict__ w_noise, const float* __restrict__ w_indiv,
    const float* __restrict__ w_social,
    const float* __restrict__ Wpk,
    const int* __restrict__ rid, const unsigned long long* __restrict__ part,
    float* __restrict__ out)
{
    __shared__ __align__(16) float W[R_*WST];
    __shared__ int   cidx_s[16][4];
    __shared__ float nz_s[B_*2];
    __shared__ float wn_s[R_], wi_s[R_], ws_s[R_];
    int tid = threadIdx.x;
    int n0 = blockIdx.x * 16;

    {
        const float4* src = (const float4*)Wpk;
        float4* dst = (float4*)W;
        for (int i = tid; i < (R_*WST)/4; i += 320) dst[i] = src[i];
    }
    if (tid < B_*2)                  nz_s[tid] = noise[tid];
    if (tid >= 64  && tid < 64+R_)   wn_s[tid-64]  = w_noise[tid-64];
    if (tid >= 96  && tid < 96+R_)   wi_s[tid-96]  = w_indiv[tid-96];
    if (tid >= 128 && tid < 128+R_)  ws_s[tid-128] = w_social[tid-128];

    if (tid >= 160 && tid < 176) {
        int n = n0 + (tid - 160);
        unsigned long long m0=0,m1=0,m2=0,m3=0;
        const unsigned long long* p = &part[(size_t)n*NSPLIT*4];
        #pragma unroll 8
        for (int j = 0; j < NSPLIT*4; ++j) INS4(m0,m1,m2,m3, p[j]);
        cidx_s[tid-160][0] = (int)(~((unsigned)(m0 & 0xffffffffull)));
        cidx_s[tid-160][1] = (int)(~((unsigned)(m1 & 0xffffffffull)));
        cidx_s[tid-160][2] = (int)(~((unsigned)(m2 & 0xffffffffull)));
        cidx_s[tid-160][3] = (int)(~((unsigned)(m3 & 0xffffffffull)));
    }
    __syncthreads();

    int n_local = tid / 20, b = tid - n_local * 20;
    int n = n0 + n_local;
    int r = rid[n];
    const float* Wr = &W[r*WST];
    float wn = wn_s[r];
    float nz0 = nz_s[b*2+0]*wn, nz1 = nz_s[b*2+1]*wn;

    float x[10][8];
    #pragma unroll
    for (int s = 0; s < 2; ++s) {
        float4 a = *(const float4*)(obsv + s*NT_ + n*8);
        float4 c = *(const float4*)(obsv + s*NT_ + n*8 + 4);
        float nz = s ? nz1 : nz0;
        x[s][0]=a.x+nz; x[s][1]=a.y+nz; x[s][2]=a.z+nz; x[s][3]=a.w+nz;
        x[s][4]=c.x+nz; x[s][5]=c.y+nz; x[s][6]=c.z+nz; x[s][7]=c.w+nz;
    }
    #pragma unroll
    for (int k = 0; k < 4; ++k) {
        int cn = cidx_s[n_local][k];
        #pragma unroll
        for (int s = 0; s < 2; ++s) {
            float4 a = *(const float4*)(obsv + s*NT_ + cn*8);
            float4 c = *(const float4*)(obsv + s*NT_ + cn*8 + 4);
            float nz = s ? nz1 : nz0;
            int ch = 2 + k*2 + s;
            x[ch][0]=a.x+nz; x[ch][1]=a.y+nz; x[ch][2]=a.z+nz; x[ch][3]=a.w+nz;
            x[ch][4]=c.x+nz; x[ch][5]=c.y+nz; x[ch][6]=c.z+nz; x[ch][7]=c.w+nz;
        }
    }

    float si[2][8];
    #pragma unroll
    for (int so = 0; so < 2; ++so) {
        float pre[8];
        float bb = Wr[672+so];
        #pragma unroll
        for (int t = 0; t < 8; ++t) pre[t] = bb;
        #pragma unroll
        for (int ci = 0; ci < 2; ++ci) {
            float w0 = Wr[so*6+ci*3+0], w1 = Wr[so*6+ci*3+1], w2 = Wr[so*6+ci*3+2];
            pre[0] += x[ci][0]*w1 + x[ci][1]*w2;
            #pragma unroll
            for (int t = 1; t < 7; ++t) pre[t] += x[ci][t-1]*w0 + x[ci][t]*w1 + x[ci][t+1]*w2;
            pre[7] += x[ci][6]*w0 + x[ci][7]*w1;
        }
        float l0 = Wr[12+so*2+0], l1 = Wr[12+so*2+1];
        float lb = Wr[674+so];
        #pragma unroll
        for (int t = 0; t < 8; ++t)
            si[so][t] = fmaxf(pre[t], 0.f) + lb + x[0][t]*l0 + x[1][t]*l1;
    }

    float ss[2][8];
    #pragma unroll
    for (int so = 0; so < 2; ++so) {
        float pre[8], lin[8];
        float bb = Wr[676+so], lb = Wr[678+so];
        #pragma unroll
        for (int t = 0; t < 8; ++t) { pre[t] = bb; lin[t] = lb; }
        #pragma unroll
        for (int ci = 0; ci < 10; ++ci) {
            float w0 = Wr[16+so*30+ci*3+0], w1 = Wr[16+so*30+ci*3+1], w2 = Wr[16+so*30+ci*3+2];
            float lw = Wr[76+so*10+ci];
            pre[0] += x[ci][0]*w1 + x[ci][1]*w2;
            #pragma unroll
            for (int t = 1; t < 7; ++t) pre[t] += x[ci][t-1]*w0 + x[ci][t]*w1 + x[ci][t+1]*w2;
            pre[7] += x[ci][6]*w0 + x[ci][7]*w1;
            #pragma unroll
            for (int t = 0; t < 8; ++t) lin[t] += x[ci][t]*lw;
        }
        #pragma unroll
        for (int t = 0; t < 8; ++t) ss[so][t] = fmaxf(pre[t], 0.f) + lin[t];
    }

    float i0[12], i1[12], s0a[12], s1a[12];
    #pragma unroll
    for (int g = 0; g < 3; ++g) {
        float4 bi = *(const float4*)(&Wr[680 + g*4]);
        float4 bs = *(const float4*)(&Wr[692 + g*4]);
        i0[g*4+0]=bi.x; i0[g*4+1]=bi.y; i0[g*4+2]=bi.z; i0[g*4+3]=bi.w;
        i1[g*4+0]=bi.x; i1[g*4+1]=bi.y; i1[g*4+2]=bi.z; i1[g*4+3]=bi.w;
        s0a[g*4+0]=bs.x; s0a[g*4+1]=bs.y; s0a[g*4+2]=bs.z; s0a[g*4+3]=bs.w;
        s1a[g*4+0]=bs.x; s1a[g*4+1]=bs.y; s1a[g*4+2]=bs.z; s1a[g*4+3]=bs.w;
    }
    #pragma unroll
    for (int t = 0; t < 8; ++t) {
        float a0 = si[0][t], a1 = si[1][t];
        float b0v = ss[0][t], b1v = ss[1][t];
        #pragma unroll
        for (int g = 0; g < 3; ++g) {
            float4 tA = *(const float4*)(&Wr[96  + t*12 + g*4]);
            float4 tB = *(const float4*)(&Wr[192 + t*12 + g*4]);
            float4 tC = *(const float4*)(&Wr[288 + t*12 + g*4]);
            float4 tD = *(const float4*)(&Wr[384 + t*12 + g*4]);
            float4 tE = *(const float4*)(&Wr[480 + t*12 + g*4]);
            float4 tF = *(const float4*)(&Wr[576 + t*12 + g*4]);
            #define UPD(co, C) do {                              \
                i0[co]  += a0*tA.C + a1*tB.C;                    \
                i1[co]  += a1*tA.C + a0*tC.C;                    \
                s0a[co] += b0v*tD.C + b1v*tE.C;                  \
                s1a[co] += b1v*tD.C + b0v*tF.C;                  \
            } while (0)
            UPD(g*4+0, x); UPD(g*4+1, y); UPD(g*4+2, z); UPD(g*4+3, w);
            #undef UPD
        }
    }

    float wi = wi_s[r], wsoc = ws_s[r];
    float o[24];
    #pragma unroll
    for (int co = 0; co < 12; ++co) {
        o[co*2+0] = wi*i0[co] + wsoc*s0a[co];
        o[co*2+1] = wi*i1[co] + wsoc*s1a[co];
    }
    float* dst = out + (size_t)(b*N_ + n)*24;
    #pragma unroll
    for (int q4 = 0; q4 < 6; ++q4)
        *(float4*)(dst + q4*4) = *(const float4*)(&o[q4*4]);
}

// ---------------------------------------------------------------------------
extern "C" void kernel_launch(void* const* d_in, const int* in_sizes, int n_in,
                              void* d_out, int out_size, void* d_ws, size_t ws_size,
                              hipStream_t stream)
{
    const float* obs      = (const float*)d_in[0];
    const float* obsv     = (const float*)d_in[1];
    const float* noise    = (const float*)d_in[2];
    const float* wq_rule  = (const float*)d_in[3];
    const float* bq_rule  = (const float*)d_in[4];
    const float* wq_ctx   = (const float*)d_in[5];
    const float* bq_ctx   = (const float*)d_in[6];
    const float* wk_ctx   = (const float*)d_in[7];
    const float* bk_ctx   = (const float*)d_in[8];
    const float* rule_emb = (const float*)d_in[9];
    const float* w_noise  = (const float*)d_in[10];
    const float* w_indiv  = (const float*)d_in[11];
    const float* w_social = (const float*)d_in[12];
    const float* sp_w  = (const float*)d_in[13];
    const float* sp_b  = (const float*)d_in[14];
    const float* spr_w = (const float*)d_in[15];
    const float* spr_b = (const float*)d_in[16];
    const float* tp_w  = (const float*)d_in[17];
    const float* tp_b  = (const float*)d_in[18];
    const float* tpr_w = (const float*)d_in[19];
    const float* tpr_b = (const float*)d_in[20];
    const float* spi_w  = (const float*)d_in[21];
    const float* spi_b  = (const float*)d_in[22];
    const float* spir_w = (const float*)d_in[23];
    const float* spir_b = (const float*)d_in[24];
    const float* tpi_w  = (const float*)d_in[25];
    const float* tpi_b  = (const float*)d_in[26];
    const float* tpir_w = (const float*)d_in[27];
    const float* tpir_b = (const float*)d_in[28];

    // workspace layout (~4.3 MB)
    char* ws = (char*)d_ws;
    float* qg = (float*)(ws);                                   // 1 MB
    float* kg = (float*)(ws + 1048576);                         // 1 MB
    unsigned long long* part = (unsigned long long*)(ws + 2097152); // 2 MB (N*16*4 u64)
    int* rid   = (int*)(ws + 4194304);                          // 16 KB
    float* Wpk = (float*)(ws + 4210688);                        // 22656 B

    hipLaunchKernelGGL(proj_prep_kernel, dim3(N_/4 + R_), dim3(256), 0, stream,
        obs, obsv, wq_ctx, bq_ctx, wk_ctx, bk_ctx, wq_rule, bq_rule, rule_emb,
        sp_w, sp_b, spr_w, spr_b, tp_w, tp_b, tpr_w, tpr_b,
        spi_w, spi_b, spir_w, spir_b, tpi_w, tpi_b, tpir_w, tpir_b,
        qg, kg, rid, Wpk);

    hipLaunchKernelGGL(attn_topk_kernel, dim3((N_/RPB)*NSPLIT), dim3(256), 0, stream,
        qg, kg, part);

    hipLaunchKernelGGL(predict_kernel, dim3(N_/16), dim3(320), 0, stream,
        obsv, noise, w_noise, w_indiv, w_social, Wpk,
        rid, part, (float*)d_out);
}

// Round 11
// 191.482 us; speedup vs baseline: 1.0690x; 1.0690x over previous
//
#include <hip/hip_runtime.h>
#include <cstdint>
#include <cstddef>

// Problem constants
#define N_   4096
#define T_   8
#define K_   4
#define R_   8
#define DK_  64
#define S_   2
#define B_   20
#define NT_  (N_*T_)

// ---------------------------------------------------------------------------
// top-4 machinery: order-preserving u64 key = (ordered_uint(value)<<32) | ~col
// larger key == larger value; tie -> smaller col wins (matches jax.lax.top_k)
// ---------------------------------------------------------------------------
__device__ __forceinline__ unsigned long long mkkey(float v, int col) {
    unsigned u = __float_as_uint(v);
    u = (u & 0x80000000u) ? ~u : (u | 0x80000000u);
    return ((unsigned long long)u << 32) | (unsigned)(~col);
}

#define INS4(t0,t1,t2,t3,keyexpr) do {                                  \
    unsigned long long _k = (keyexpr);                                  \
    if (_k > (t3)) {                                                    \
        bool _g2 = _k > (t2), _g1 = _k > (t1), _g0 = _k > (t0);         \
        (t3) = _g2 ? (t2) : _k;                                         \
        (t2) = _g2 ? (_g1 ? (t1) : _k) : (t2);                          \
        (t1) = _g1 ? (_g0 ? (t0) : _k) : (t1);                          \
        (t0) = _g0 ? _k : (t0);                                         \
    }                                                                   \
} while (0)

__device__ __forceinline__ unsigned long long shfl_xor_u64(unsigned long long v, int m) {
    unsigned lo = (unsigned)v, hi = (unsigned)(v >> 32);
    lo = __shfl_xor(lo, m, 64);
    hi = __shfl_xor(hi, m, 64);
    return ((unsigned long long)hi << 32) | lo;
}

#define WST 708

// ---------------------------------------------------------------------------
// Kernel A: proj + prep in ONE dispatch (unchanged from R8).
// ---------------------------------------------------------------------------
__global__ __launch_bounds__(256) void proj_prep_kernel(
    const float* __restrict__ obs, const float* __restrict__ obsv,
    const float* __restrict__ wq_ctx, const float* __restrict__ bq_ctx,
    const float* __restrict__ wk_ctx, const float* __restrict__ bk_ctx,
    const float* __restrict__ wq_rule, const float* __restrict__ bq_rule,
    const float* __restrict__ rule_emb,
    const float* __restrict__ sp_w, const float* __restrict__ sp_b,
    const float* __restrict__ spr_w, const float* __restrict__ spr_b,
    const float* __restrict__ tp_w, const float* __restrict__ tp_b,
    const float* __restrict__ tpr_w, const float* __restrict__ tpr_b,
    const float* __restrict__ spi_w, const float* __restrict__ spi_b,
    const float* __restrict__ spir_w, const float* __restrict__ spir_b,
    const float* __restrict__ tpi_w, const float* __restrict__ tpi_b,
    const float* __restrict__ tpir_w, const float* __restrict__ tpir_b,
    float* __restrict__ qg, float* __restrict__ kg, int* __restrict__ rid,
    float* __restrict__ Wpk)
{
    if (blockIdx.x >= N_/4) {
        int r = blockIdx.x - N_/4;
        for (int o = threadIdx.x; o < 704; o += 256) {
            float v;
            if (o < 12)      v = spi_w[r*12 + o];
            else if (o < 16) v = spir_w[r*4 + (o-12)];
            else if (o < 76) v = sp_w[r*60 + (o-16)];
            else if (o < 96) v = spr_w[r*20 + (o-76)];
            else if (o < 192) { int q=o-96;  int t=q/12, co=q%12; v = tpi_w[((r*12+co)*8+t)*3+1] + tpir_w[(r*12+co)*8+t]; }
            else if (o < 288) { int q=o-192; int t=q/12, co=q%12; v = tpi_w[((r*12+co)*8+t)*3+2]; }
            else if (o < 384) { int q=o-288; int t=q/12, co=q%12; v = tpi_w[((r*12+co)*8+t)*3+0]; }
            else if (o < 480) { int q=o-384; int t=q/12, co=q%12; v = tp_w[((r*12+co)*8+t)*3+1] + tpr_w[(r*12+co)*8+t]; }
            else if (o < 576) { int q=o-480; int t=q/12, co=q%12; v = tp_w[((r*12+co)*8+t)*3+2]; }
            else if (o < 672) { int q=o-576; int t=q/12, co=q%12; v = tp_w[((r*12+co)*8+t)*3+0]; }
            else if (o < 674) v = spi_b[r*2 + (o-672)];
            else if (o < 676) v = spir_b[r*2 + (o-674)];
            else if (o < 678) v = sp_b[r*2 + (o-676)];
            else if (o < 680) v = spr_b[r*2 + (o-678)];
            else if (o < 692) v = tpi_b[r*12 + (o-680)] + tpir_b[r*12 + (o-680)];
            else              v = tp_b[r*12 + (o-692)] + tpr_b[r*12 + (o-692)];
            Wpk[r*WST + o] = v;
        }
        return;
    }

    int wv = threadIdx.x >> 6, d = threadIdx.x & 63;
    int n = blockIdx.x * 4 + wv;
    __shared__ float xs[4][32];
    if (d < 32) {
        int t = d >> 2, c = d & 3;
        const float* src = (c < 2) ? obs : obsv;
        xs[wv][d] = src[(c & 1) * NT_ + n * T_ + t];
    }
    __syncthreads();
    const float* x = xs[wv];
    float q = bq_ctx[d], k = bk_ctx[d], rq = bq_rule[d];
    #pragma unroll
    for (int i = 0; i < 32; ++i) {
        float xv = x[i];
        q = fmaf(xv, wq_ctx[i*64 + d], q);
        k = fmaf(xv, wk_ctx[i*64 + d], k);
    }
    #pragma unroll
    for (int i = 0; i < 16; ++i) {
        int t = i >> 1, s = i & 1;
        rq = fmaf(x[t*4 + 2 + s], wq_rule[i*64 + d], rq);
    }
    qg[n*64 + d] = q;
    kg[n*64 + d] = k;

    float best = -1e30f; int bestr = 0;
    #pragma unroll
    for (int r = 0; r < 8; ++r) {
        float p = rq * rule_emb[r*64 + d];
        #pragma unroll
        for (int off = 32; off > 0; off >>= 1) p += __shfl_xor(p, off, 64);
        if (p > best) { best = p; bestr = r; }
    }
    if (d == 0) rid[n] = bestr;
}

// ---------------------------------------------------------------------------
// Kernel B: logits = q@k^T fused with per-row top-4.
// R10: REVERT to the best-measured R4 configuration (62 µs) — the tile-space
// sweep (R4..R9) showed the kernel is latency/structure-bound: wall tracks
// waves/CU first, LDS traffic second.  4x4 tile @ 16 waves/CU with the
// smallest LDS footprint (34816 B -> 4 blocks/CU) wins:
//   4x4 @16w = 62 | 4x8 @12w = 67 | 4x8 @16w(512t) = 65.5 | 8x8 @8w = 73.5
// 2D register tiling: 256 thr as 16x16 (tx=tid&15, ty=tid>>4); thread owns a
// 4x4 C-tile.  q,k staged transposed [d][row/col] at stride 68; butterfly
// register merge over the 16 tx lanes.  Conflicts measured 0.
// ---------------------------------------------------------------------------
#define RPB     64                   // rows per block
#define CTILE   64                   // cols per LDS tile
#define NSPLIT  16                   // col splits; 4096/16 = 256 cols/block
#define DPAD    68                   // [d][*] LDS row stride in floats

__global__ __launch_bounds__(256) void attn_topk_kernel(
    const float* __restrict__ qg, const float* __restrict__ kg,
    unsigned long long* __restrict__ part)
{
    __shared__ float qT[DK_*DPAD];                  // 17408 B
    __shared__ float kT[DK_*DPAD];                  // 17408 B

    int tid = threadIdx.x;
    int tx = tid & 15, ty = tid >> 4;
    int rowblk = blockIdx.x >> 4, split = blockIdx.x & 15;
    int row0 = rowblk * RPB;
    int colbase = split * (N_ / NSPLIT);

    // stage qT[d][row] once: row=chunk&63 (==lane), dchunk=chunk>>6;
    // LDS write banks (const+lane)%32 -> 2-way, free.
    #pragma unroll
    for (int i = 0; i < 4; ++i) {
        int chunk = tid + 256*i;
        int row = chunk & 63, dchunk = chunk >> 6;
        float4 v = *(const float4*)(qg + (size_t)(row0 + row)*64 + 4*dchunk);
        qT[(4*dchunk+0)*DPAD + row] = v.x;
        qT[(4*dchunk+1)*DPAD + row] = v.y;
        qT[(4*dchunk+2)*DPAD + row] = v.z;
        qT[(4*dchunk+3)*DPAD + row] = v.w;
    }

    // top-4 state: 4 rows x 4 slots, named scalars (0 < any finite key)
    unsigned long long T0a=0,T0b=0,T0c=0,T0d=0;
    unsigned long long T1a=0,T1b=0,T1c=0,T1d=0;
    unsigned long long T2a=0,T2b=0,T2c=0,T2d=0;
    unsigned long long T3a=0,T3b=0,T3c=0,T3d=0;

    for (int tile = 0; tile < (N_/NSPLIT)/CTILE; ++tile) {   // 4 tiles
        int c0 = colbase + tile * CTILE;
        __syncthreads();                            // kT free
        #pragma unroll
        for (int i = 0; i < 4; ++i) {
            int chunk = tid + 256*i;
            int col = chunk & 63, dchunk = chunk >> 6;
            float4 v = *(const float4*)(kg + (size_t)(c0 + col)*64 + 4*dchunk);
            kT[(4*dchunk+0)*DPAD + col] = v.x;
            kT[(4*dchunk+1)*DPAD + col] = v.y;
            kT[(4*dchunk+2)*DPAD + col] = v.z;
            kT[(4*dchunk+3)*DPAD + col] = v.w;
        }
        __syncthreads();

        float c00=0,c01=0,c02=0,c03=0, c10=0,c11=0,c12=0,c13=0;
        float c20=0,c21=0,c22=0,c23=0, c30=0,c31=0,c32=0,c33=0;

        #pragma unroll 4
        for (int d = 0; d < 64; ++d) {
            float4 a = *(const float4*)(&qT[d*DPAD + 4*ty]);    // broadcast x4
            float4 b = *(const float4*)(&kT[d*DPAD + 4*tx]);    // 2-phase, free
            c00 = fmaf(a.x, b.x, c00); c01 = fmaf(a.x, b.y, c01);
            c02 = fmaf(a.x, b.z, c02); c03 = fmaf(a.x, b.w, c03);
            c10 = fmaf(a.y, b.x, c10); c11 = fmaf(a.y, b.y, c11);
            c12 = fmaf(a.y, b.z, c12); c13 = fmaf(a.y, b.w, c13);
            c20 = fmaf(a.z, b.x, c20); c21 = fmaf(a.z, b.y, c21);
            c22 = fmaf(a.z, b.z, c22); c23 = fmaf(a.z, b.w, c23);
            c30 = fmaf(a.w, b.x, c30); c31 = fmaf(a.w, b.y, c31);
            c32 = fmaf(a.w, b.z, c32); c33 = fmaf(a.w, b.w, c33);
        }
        int cc = c0 + 4*tx;
        INS4(T0a,T0b,T0c,T0d, mkkey(c00, cc+0));
        INS4(T0a,T0b,T0c,T0d, mkkey(c01, cc+1));
        INS4(T0a,T0b,T0c,T0d, mkkey(c02, cc+2));
        INS4(T0a,T0b,T0c,T0d, mkkey(c03, cc+3));
        INS4(T1a,T1b,T1c,T1d, mkkey(c10, cc+0));
        INS4(T1a,T1b,T1c,T1d, mkkey(c11, cc+1));
        INS4(T1a,T1b,T1c,T1d, mkkey(c12, cc+2));
        INS4(T1a,T1b,T1c,T1d, mkkey(c13, cc+3));
        INS4(T2a,T2b,T2c,T2d, mkkey(c20, cc+0));
        INS4(T2a,T2b,T2c,T2d, mkkey(c21, cc+1));
        INS4(T2a,T2b,T2c,T2d, mkkey(c22, cc+2));
        INS4(T2a,T2b,T2c,T2d, mkkey(c23, cc+3));
        INS4(T3a,T3b,T3c,T3d, mkkey(c30, cc+0));
        INS4(T3a,T3b,T3c,T3d, mkkey(c31, cc+1));
        INS4(T3a,T3b,T3c,T3d, mkkey(c32, cc+2));
        INS4(T3a,T3b,T3c,T3d, mkkey(c33, cc+3));
    }

    // butterfly merge across the 16 tx lanes sharing each row group.
    // SNAPSHOT partner's keys before merging (lockstep hazard), then INS4.
    #pragma unroll
    for (int m = 1; m < 16; m <<= 1) {
        unsigned long long r0, r1, r2, r3;
        r0 = shfl_xor_u64(T0a, m); r1 = shfl_xor_u64(T0b, m);
        r2 = shfl_xor_u64(T0c, m); r3 = shfl_xor_u64(T0d, m);
        INS4(T0a,T0b,T0c,T0d, r0); INS4(T0a,T0b,T0c,T0d, r1);
        INS4(T0a,T0b,T0c,T0d, r2); INS4(T0a,T0b,T0c,T0d, r3);
        r0 = shfl_xor_u64(T1a, m); r1 = shfl_xor_u64(T1b, m);
        r2 = shfl_xor_u64(T1c, m); r3 = shfl_xor_u64(T1d, m);
        INS4(T1a,T1b,T1c,T1d, r0); INS4(T1a,T1b,T1c,T1d, r1);
        INS4(T1a,T1b,T1c,T1d, r2); INS4(T1a,T1b,T1c,T1d, r3);
        r0 = shfl_xor_u64(T2a, m); r1 = shfl_xor_u64(T2b, m);
        r2 = shfl_xor_u64(T2c, m); r3 = shfl_xor_u64(T2d, m);
        INS4(T2a,T2b,T2c,T2d, r0); INS4(T2a,T2b,T2c,T2d, r1);
        INS4(T2a,T2b,T2c,T2d, r2); INS4(T2a,T2b,T2c,T2d, r3);
        r0 = shfl_xor_u64(T3a, m); r1 = shfl_xor_u64(T3b, m);
        r2 = shfl_xor_u64(T3c, m); r3 = shfl_xor_u64(T3d, m);
        INS4(T3a,T3b,T3c,T3d, r0); INS4(T3a,T3b,T3c,T3d, r1);
        INS4(T3a,T3b,T3c,T3d, r2); INS4(T3a,T3b,T3c,T3d, r3);
    }

    if (tx == 0) {
        unsigned long long* q;
        q = &part[(size_t)((row0 + 4*ty + 0)*NSPLIT + split)*4];
        q[0]=T0a; q[1]=T0b; q[2]=T0c; q[3]=T0d;
        q = &part[(size_t)((row0 + 4*ty + 1)*NSPLIT + split)*4];
        q[0]=T1a; q[1]=T1b; q[2]=T1c; q[3]=T1d;
        q = &part[(size_t)((row0 + 4*ty + 2)*NSPLIT + split)*4];
        q[0]=T2a; q[1]=T2b; q[2]=T2c; q[3]=T2d;
        q = &part[(size_t)((row0 + 4*ty + 3)*NSPLIT + split)*4];
        q[0]=T3a; q[1]=T3b; q[2]=T3c; q[3]=T3d;
    }
}

// ---------------------------------------------------------------------------
// Kernel C: merge + predict fused (unchanged from R8).
// ---------------------------------------------------------------------------
__global__ __launch_bounds__(320) void predict_kernel(
    const float* __restrict__ obsv, const float* __restrict__ noise,
    const float* __restrict__ w_noise, const float* __restrict__ w_indiv,
    const float* __restrict__ w_social,
    const float* __restrict__ Wpk,
    const int* __restrict__ rid, const unsigned long long* __restrict__ part,
    float* __restrict__ out)
{
    __shared__ __align__(16) float W[R_*WST];
    __shared__ int   cidx_s[16][4];
    __shared__ float nz_s[B_*2];
    __shared__ float wn_s[R_], wi_s[R_], ws_s[R_];
    int tid = threadIdx.x;
    int n0 = blockIdx.x * 16;

    {
        const float4* src = (const float4*)Wpk;
        float4* dst = (float4*)W;
        for (int i = tid; i < (R_*WST)/4; i += 320) dst[i] = src[i];
    }
    if (tid < B_*2)                  nz_s[tid] = noise[tid];
    if (tid >= 64  && tid < 64+R_)   wn_s[tid-64]  = w_noise[tid-64];
    if (tid >= 96  && tid < 96+R_)   wi_s[tid-96]  = w_indiv[tid-96];
    if (tid >= 128 && tid < 128+R_)  ws_s[tid-128] = w_social[tid-128];

    if (tid >= 160 && tid < 176) {
        int n = n0 + (tid - 160);
        unsigned long long m0=0,m1=0,m2=0,m3=0;
        const unsigned long long* p = &part[(size_t)n*NSPLIT*4];
        #pragma unroll 8
        for (int j = 0; j < NSPLIT*4; ++j) INS4(m0,m1,m2,m3, p[j]);
        cidx_s[tid-160][0] = (int)(~((unsigned)(m0 & 0xffffffffull)));
        cidx_s[tid-160][1] = (int)(~((unsigned)(m1 & 0xffffffffull)));
        cidx_s[tid-160][2] = (int)(~((unsigned)(m2 & 0xffffffffull)));
        cidx_s[tid-160][3] = (int)(~((unsigned)(m3 & 0xffffffffull)));
    }
    __syncthreads();

    int n_local = tid / 20, b = tid - n_local * 20;
    int n = n0 + n_local;
    int r = rid[n];
    const float* Wr = &W[r*WST];
    float wn = wn_s[r];
    float nz0 = nz_s[b*2+0]*wn, nz1 = nz_s[b*2+1]*wn;

    float x[10][8];
    #pragma unroll
    for (int s = 0; s < 2; ++s) {
        float4 a = *(const float4*)(obsv + s*NT_ + n*8);
        float4 c = *(const float4*)(obsv + s*NT_ + n*8 + 4);
        float nz = s ? nz1 : nz0;
        x[s][0]=a.x+nz; x[s][1]=a.y+nz; x[s][2]=a.z+nz; x[s][3]=a.w+nz;
        x[s][4]=c.x+nz; x[s][5]=c.y+nz; x[s][6]=c.z+nz; x[s][7]=c.w+nz;
    }
    #pragma unroll
    for (int k = 0; k < 4; ++k) {
        int cn = cidx_s[n_local][k];
        #pragma unroll
        for (int s = 0; s < 2; ++s) {
            float4 a = *(const float4*)(obsv + s*NT_ + cn*8);
            float4 c = *(const float4*)(obsv + s*NT_ + cn*8 + 4);
            float nz = s ? nz1 : nz0;
            int ch = 2 + k*2 + s;
            x[ch][0]=a.x+nz; x[ch][1]=a.y+nz; x[ch][2]=a.z+nz; x[ch][3]=a.w+nz;
            x[ch][4]=c.x+nz; x[ch][5]=c.y+nz; x[ch][6]=c.z+nz; x[ch][7]=c.w+nz;
        }
    }

    float si[2][8];
    #pragma unroll
    for (int so = 0; so < 2; ++so) {
        float pre[8];
        float bb = Wr[672+so];
        #pragma unroll
        for (int t = 0; t < 8; ++t) pre[t] = bb;
        #pragma unroll
        for (int ci = 0; ci < 2; ++ci) {
            float w0 = Wr[so*6+ci*3+0], w1 = Wr[so*6+ci*3+1], w2 = Wr[so*6+ci*3+2];
            pre[0] += x[ci][0]*w1 + x[ci][1]*w2;
            #pragma unroll
            for (int t = 1; t < 7; ++t) pre[t] += x[ci][t-1]*w0 + x[ci][t]*w1 + x[ci][t+1]*w2;
            pre[7] += x[ci][6]*w0 + x[ci][7]*w1;
        }
        float l0 = Wr[12+so*2+0], l1 = Wr[12+so*2+1];
        float lb = Wr[674+so];
        #pragma unroll
        for (int t = 0; t < 8; ++t)
            si[so][t] = fmaxf(pre[t], 0.f) + lb + x[0][t]*l0 + x[1][t]*l1;
    }

    float ss[2][8];
    #pragma unroll
    for (int so = 0; so < 2; ++so) {
        float pre[8], lin[8];
        float bb = Wr[676+so], lb = Wr[678+so];
        #pragma unroll
        for (int t = 0; t < 8; ++t) { pre[t] = bb; lin[t] = lb; }
        #pragma unroll
        for (int ci = 0; ci < 10; ++ci) {
            float w0 = Wr[16+so*30+ci*3+0], w1 = Wr[16+so*30+ci*3+1], w2 = Wr[16+so*30+ci*3+2];
            float lw = Wr[76+so*10+ci];
            pre[0] += x[ci][0]*w1 + x[ci][1]*w2;
            #pragma unroll
            for (int t = 1; t < 7; ++t) pre[t] += x[ci][t-1]*w0 + x[ci][t]*w1 + x[ci][t+1]*w2;
            pre[7] += x[ci][6]*w0 + x[ci][7]*w1;
            #pragma unroll
            for (int t = 0; t < 8; ++t) lin[t] += x[ci][t]*lw;
        }
        #pragma unroll
        for (int t = 0; t < 8; ++t) ss[so][t] = fmaxf(pre[t], 0.f) + lin[t];
    }

    float i0[12], i1[12], s0a[12], s1a[12];
    #pragma unroll
    for (int g = 0; g < 3; ++g) {
        float4 bi = *(const float4*)(&Wr[680 + g*4]);
        float4 bs = *(const float4*)(&Wr[692 + g*4]);
        i0[g*4+0]=bi.x; i0[g*4+1]=bi.y; i0[g*4+2]=bi.z; i0[g*4+3]=bi.w;
        i1[g*4+0]=bi.x; i1[g*4+1]=bi.y; i1[g*4+2]=bi.z; i1[g*4+3]=bi.w;
        s0a[g*4+0]=bs.x; s0a[g*4+1]=bs.y; s0a[g*4+2]=bs.z; s0a[g*4+3]=bs.w;
        s1a[g*4+0]=bs.x; s1a[g*4+1]=bs.y; s1a[g*4+2]=bs.z; s1a[g*4+3]=bs.w;
    }
    #pragma unroll
    for (int t = 0; t < 8; ++t) {
        float a0 = si[0][t], a1 = si[1][t];
        float b0v = ss[0][t], b1v = ss[1][t];
        #pragma unroll
        for (int g = 0; g < 3; ++g) {
            float4 tA = *(const float4*)(&Wr[96  + t*12 + g*4]);
            float4 tB = *(const float4*)(&Wr[192 + t*12 + g*4]);
            float4 tC = *(const float4*)(&Wr[288 + t*12 + g*4]);
            float4 tD = *(const float4*)(&Wr[384 + t*12 + g*4]);
            float4 tE = *(const float4*)(&Wr[480 + t*12 + g*4]);
            float4 tF = *(const float4*)(&Wr[576 + t*12 + g*4]);
            #define UPD(co, C) do {                              \
                i0[co]  += a0*tA.C + a1*tB.C;                    \
                i1[co]  += a1*tA.C + a0*tC.C;                    \
                s0a[co] += b0v*tD.C + b1v*tE.C;                  \
                s1a[co] += b1v*tD.C + b0v*tF.C;                  \
            } while (0)
            UPD(g*4+0, x); UPD(g*4+1, y); UPD(g*4+2, z); UPD(g*4+3, w);
            #undef UPD
        }
    }

    float wi = wi_s[r], wsoc = ws_s[r];
    float o[24];
    #pragma unroll
    for (int co = 0; co < 12; ++co) {
        o[co*2+0] = wi*i0[co] + wsoc*s0a[co];
        o[co*2+1] = wi*i1[co] + wsoc*s1a[co];
    }
    float* dst = out + (size_t)(b*N_ + n)*24;
    #pragma unroll
    for (int q4 = 0; q4 < 6; ++q4)
        *(float4*)(dst + q4*4) = *(const float4*)(&o[q4*4]);
}

// ---------------------------------------------------------------------------
extern "C" void kernel_launch(void* const* d_in, const int* in_sizes, int n_in,
                              void* d_out, int out_size, void* d_ws, size_t ws_size,
                              hipStream_t stream)
{
    const float* obs      = (const float*)d_in[0];
    const float* obsv     = (const float*)d_in[1];
    const float* noise    = (const float*)d_in[2];
    const float* wq_rule  = (const float*)d_in[3];
    const float* bq_rule  = (const float*)d_in[4];
    const float* wq_ctx   = (const float*)d_in[5];
    const float* bq_ctx   = (const float*)d_in[6];
    const float* wk_ctx   = (const float*)d_in[7];
    const float* bk_ctx   = (const float*)d_in[8];
    const float* rule_emb = (const float*)d_in[9];
    const float* w_noise  = (const float*)d_in[10];
    const float* w_indiv  = (const float*)d_in[11];
    const float* w_social = (const float*)d_in[12];
    const float* sp_w  = (const float*)d_in[13];
    const float* sp_b  = (const float*)d_in[14];
    const float* spr_w = (const float*)d_in[15];
    const float* spr_b = (const float*)d_in[16];
    const float* tp_w  = (const float*)d_in[17];
    const float* tp_b  = (const float*)d_in[18];
    const float* tpr_w = (const float*)d_in[19];
    const float* tpr_b = (const float*)d_in[20];
    const float* spi_w  = (const float*)d_in[21];
    const float* spi_b  = (const float*)d_in[22];
    const float* spir_w = (const float*)d_in[23];
    const float* spir_b = (const float*)d_in[24];
    const float* tpi_w  = (const float*)d_in[25];
    const float* tpi_b  = (const float*)d_in[26];
    const float* tpir_w = (const float*)d_in[27];
    const float* tpir_b = (const float*)d_in[28];

    // workspace layout (~4.3 MB)
    char* ws = (char*)d_ws;
    float* qg = (float*)(ws);                                   // 1 MB
    float* kg = (float*)(ws + 1048576);                         // 1 MB
    unsigned long long* part = (unsigned long long*)(ws + 2097152); // 2 MB (N*16*4 u64)
    int* rid   = (int*)(ws + 4194304);                          // 16 KB
    float* Wpk = (float*)(ws + 4210688);                        // 22656 B

    hipLaunchKernelGGL(proj_prep_kernel, dim3(N_/4 + R_), dim3(256), 0, stream,
        obs, obsv, wq_ctx, bq_ctx, wk_ctx, bk_ctx, wq_rule, bq_rule, rule_emb,
        sp_w, sp_b, spr_w, spr_b, tp_w, tp_b, tpr_w, tpr_b,
        spi_w, spi_b, spir_w, spir_b, tpi_w, tpi_b, tpir_w, tpir_b,
        qg, kg, rid, Wpk);

    hipLaunchKernelGGL(attn_topk_kernel, dim3((N_/RPB)*NSPLIT), dim3(256), 0, stream,
        qg, kg, part);

    hipLaunchKernelGGL(predict_kernel, dim3(N_/16), dim3(320), 0, stream,
        obsv, noise, w_noise, w_indiv, w_social, Wpk,
        rid, part, (float*)d_out);
}